// Round 7
// baseline (299.800 us; speedup 1.0000x reference)
//
#include <hip/hip_runtime.h>
#include <math.h>

// v6: proj with ZERO LDS / ZERO in-loop barriers. MFMA fragments loaded
// directly from global (A per-lane fp32->bf16 in regs, W from L2-resident
// Wt). A prefetched 2 K-steps ahead (covers ~900cy HBM), W 1 step (~200cy
// L2). Attacks the measured invariant: all 5 barrier-gated structures
// capped at ~2.1 TB/s A-consumption (duty-limited in-flight bytes).
// wtrans/flash/combine unchanged (frozen).

constexpr int BATCH  = 8;
constexpr int SEQQ   = 2048;
constexpr int SEQK   = 2048;
constexpr int DMODEL = 1024;
constexpr int ODIM   = 128;

typedef __attribute__((ext_vector_type(8))) short bf16x8;
typedef __attribute__((ext_vector_type(4))) float f32x4;

__device__ inline unsigned short f2bf(float f) {   // RNE
    union { float f; unsigned int u; } v; v.f = f;
    unsigned int r = v.u + 0x7FFFu + ((v.u >> 16) & 1u);
    return (unsigned short)(r >> 16);
}

// pack two fp32 -> 2 bf16, round-half-up (v_add + v_perm, 3 instr)
__device__ __forceinline__ unsigned int pk2bf(float a, float b) {
    unsigned int ua = __float_as_uint(a) + 0x8000u;
    unsigned int ub = __float_as_uint(b) + 0x8000u;
    return __builtin_amdgcn_perm(ub, ua, 0x07060302u);
}

__device__ __forceinline__ void gl_lds16(const void* g, void* l) {
    __builtin_amdgcn_global_load_lds(
        (const __attribute__((address_space(1))) unsigned int*)g,
        (__attribute__((address_space(3))) unsigned int*)l, 16, 0, 0);
}

// ---------------------------------------------------------------------------
// W[1024][128] fp32  ->  Wt[128][1024] bf16   (x3 via blockIdx.z)
// ---------------------------------------------------------------------------
__global__ __launch_bounds__(256)
void wtrans_kernel(const float* __restrict__ Wq, const float* __restrict__ Wk,
                   const float* __restrict__ Wv, unsigned short* __restrict__ Wt)
{
    const int which = blockIdx.z;
    const float* __restrict__ W = which == 0 ? Wq : (which == 1 ? Wk : Wv);
    unsigned short* __restrict__ dst = Wt + (size_t)which * DMODEL * ODIM;
    const int k0 = blockIdx.x * 32, n0 = blockIdx.y * 32;
    __shared__ unsigned short T[32][36];
    const int t = threadIdx.x;
    const int r = t >> 3, c = (t & 7) * 4;
    float4 w = *(const float4*)(W + (size_t)(k0 + r) * ODIM + n0 + c);
    T[r][c + 0] = f2bf(w.x); T[r][c + 1] = f2bf(w.y);
    T[r][c + 2] = f2bf(w.z); T[r][c + 3] = f2bf(w.w);
    __syncthreads();
    const int n = t >> 3, k4 = (t & 7) * 4;
    ushort4 o;
    o.x = T[k4 + 0][n]; o.y = T[k4 + 1][n];
    o.z = T[k4 + 2][n]; o.w = T[k4 + 3][n];
    *(ushort4*)(dst + (size_t)(n0 + n) * DMODEL + k0 + k4) = o;
}

// ---------------------------------------------------------------------------
// Projection v6: global-direct MFMA, no LDS, no in-loop barriers.
// Grid (128,3) = 384 blocks, 4 waves, wave = 32 rows x 128 cols.
// Per K-step (K=32): 2 A-frags (per-lane 8 fp32 = 2 float4, rows
// row0+wrh+mt*16+lrow, k = ks*32+quad*8) -> pk2bf -> 16 MFMA with 8 W-frags
// (Wt[nt*16+lrow][ks*32+quad*8], bf16, L2-hot). A triple-buffered (t+2
// prefetch), W double-buffered (t+1). Register-only pipeline: hardware
// vmcnt scheduling keeps many loads in flight, no barrier quantization.
// ---------------------------------------------------------------------------
#define PST(CA, PA, CW, PW, T, PFA, PFW)                                      \
  {                                                                            \
    if (PFA) {                                                                 \
      const int ko = ((T) + 2) * 32;                                           \
      _Pragma("unroll")                                                        \
      for (int mt = 0; mt < 2; ++mt) {                                         \
        PA[mt][0] = *(const float4*)(ap[mt] + ko);                             \
        PA[mt][1] = *(const float4*)(ap[mt] + ko + 4);                         \
      }                                                                        \
    }                                                                          \
    if (PFW) {                                                                 \
      const int kw = ((T) + 1) * 32;                                           \
      _Pragma("unroll")                                                        \
      for (int nt = 0; nt < 8; ++nt)                                           \
        PW[nt] = *(const bf16x8*)(wp + nt * 16 * DMODEL + kw);                 \
    }                                                                          \
    bf16x8 af[2];                                                              \
    _Pragma("unroll")                                                          \
    for (int mt = 0; mt < 2; ++mt) {                                           \
      ((unsigned int*)&af[mt])[0] = pk2bf(CA[mt][0].x, CA[mt][0].y);           \
      ((unsigned int*)&af[mt])[1] = pk2bf(CA[mt][0].z, CA[mt][0].w);           \
      ((unsigned int*)&af[mt])[2] = pk2bf(CA[mt][1].x, CA[mt][1].y);           \
      ((unsigned int*)&af[mt])[3] = pk2bf(CA[mt][1].z, CA[mt][1].w);           \
    }                                                                          \
    _Pragma("unroll")                                                          \
    for (int nt = 0; nt < 8; ++nt)                                             \
      _Pragma("unroll")                                                        \
      for (int mt = 0; mt < 2; ++mt)                                           \
        acc[mt][nt] = __builtin_amdgcn_mfma_f32_16x16x32_bf16(                 \
            af[mt], CW[nt], acc[mt][nt], 0, 0, 0);                             \
  }

__global__ __launch_bounds__(256, 2)
void proj_kernel(const float* __restrict__ Aq, const float* __restrict__ Ak,
                 const float* __restrict__ Av,
                 const unsigned short* __restrict__ Wt_all,
                 const float* __restrict__ bq, const float* __restrict__ bk,
                 const float* __restrict__ bv,
                 unsigned short* __restrict__ Qb, unsigned short* __restrict__ Kb,
                 unsigned short* __restrict__ Vt)
{
    const int which = blockIdx.y;
    const float* __restrict__ A    = which == 0 ? Aq : (which == 1 ? Ak : Av);
    const float* __restrict__ bias = which == 0 ? bq : (which == 1 ? bk : bv);
    const unsigned short* __restrict__ Wt = Wt_all + (size_t)which * DMODEL * ODIM;

    const int row0 = blockIdx.x * 128;
    const int t = threadIdx.x, wave = t >> 6, lane = t & 63;
    const int lrow = lane & 15, quad = lane >> 4;
    const int wrh = wave * 32;          // wave row base: 32 rows, all 128 cols

    // per-lane fragment base pointers
    const float* ap[2];
    ap[0] = A + (size_t)(row0 + wrh + lrow) * DMODEL + quad * 8;
    ap[1] = ap[0] + (size_t)16 * DMODEL;
    const unsigned short* wp = Wt + (size_t)lrow * DMODEL + quad * 8;

    f32x4 acc[2][8];
#pragma unroll
    for (int mt = 0; mt < 2; ++mt)
#pragma unroll
        for (int nt = 0; nt < 8; ++nt)
#pragma unroll
            for (int i = 0; i < 4; ++i) acc[mt][nt][i] = 0.f;

    // A: 3 buffers (step t%3), W: 2 buffers (step t%2)
    float4 Aa[2][2], Ab[2][2], Ac[2][2];
    bf16x8 Wu[8], Wv_[8];

    // prologue: A(0)->Aa, A(1)->Ab, W(0)->Wu
#pragma unroll
    for (int mt = 0; mt < 2; ++mt) {
        Aa[mt][0] = *(const float4*)(ap[mt]);
        Aa[mt][1] = *(const float4*)(ap[mt] + 4);
        Ab[mt][0] = *(const float4*)(ap[mt] + 32);
        Ab[mt][1] = *(const float4*)(ap[mt] + 36);
    }
#pragma unroll
    for (int nt = 0; nt < 8; ++nt)
        Wu[nt] = *(const bf16x8*)(wp + nt * 16 * DMODEL);

    // 32 K-steps; step t: A buf t%3 (a,b,c), W buf t%2 (u,v).
    // pf A(t+2) -> (t+2)%3, pf W(t+1) -> (t+1)%2.
    for (int kt = 0; kt < 30; kt += 6) {
        PST(Aa, Ac, Wu, Wv_, kt + 0, 1, 1);
        PST(Ab, Aa, Wv_, Wu, kt + 1, 1, 1);
        PST(Ac, Ab, Wu, Wv_, kt + 2, 1, 1);
        PST(Aa, Ac, Wv_, Wu, kt + 3, 1, 1);
        PST(Ab, Aa, Wu, Wv_, kt + 4, 1, 1);
        PST(Ac, Ab, Wv_, Wu, kt + 5, 1, 1);
    }
    // steps 30, 31 (A31 already prefetched into Ab at step 29; W30 in Wu)
    PST(Aa, Ac, Wu, Wv_, 30, 0, 1);   // pf W(31) -> Wv_
    PST(Ab, Aa, Wv_, Wu, 31, 0, 0);

    const float sc = (which == 0) ? 0.08838834764831845f : 1.0f;
    float bv_[8];
#pragma unroll
    for (int nt = 0; nt < 8; ++nt) bv_[nt] = bias[nt * 16 + lrow];

    const int b  = row0 >> 11;
    const int mb = row0 & 2047;

    if (which == 2) {
        // V transposed store: Vt[b][n][m]
#pragma unroll
        for (int mt = 0; mt < 2; ++mt)
#pragma unroll
            for (int nt = 0; nt < 8; ++nt) {
                const int n = nt * 16 + lrow;
                ushort4 o;
                o.x = f2bf(acc[mt][nt][0] + bv_[nt]);
                o.y = f2bf(acc[mt][nt][1] + bv_[nt]);
                o.z = f2bf(acc[mt][nt][2] + bv_[nt]);
                o.w = f2bf(acc[mt][nt][3] + bv_[nt]);
                *(ushort4*)(Vt + ((size_t)b * ODIM + n) * SEQK
                            + mb + wrh + mt * 16 + quad * 4) = o;
            }
    } else {
        unsigned short* __restrict__ Ob = (which == 0) ? Qb : Kb;
#pragma unroll
        for (int mt = 0; mt < 2; ++mt)
#pragma unroll
            for (int nt = 0; nt < 8; ++nt)
#pragma unroll
                for (int r = 0; r < 4; ++r) {
                    float val = sc * (acc[mt][nt][r] + bv_[nt]);
                    Ob[(size_t)(row0 + wrh + mt * 16 + quad * 4 + r) * ODIM
                       + nt * 16 + lrow] = f2bf(val);
                }
    }
}

// ---------------------------------------------------------------------------
// Flash attention: staged K/V (async swizzled gl_lds16), non-online softmax,
// key-split. Block 256 thr = 4 waves x 16 Q-rows = 64 rows; key chunk 64.
// LDS 41.2KB -> 3 blocks/CU. Dead splits write l=0 only.
// ---------------------------------------------------------------------------
__global__ __launch_bounds__(256, 3)
void flash_kernel(const unsigned short* __restrict__ Qb,
                  const unsigned short* __restrict__ Kb,
                  const unsigned short* __restrict__ Vt,
                  const int* __restrict__ valid_lens,
                  float* __restrict__ Op, float* __restrict__ Lp, int nsplit)
{
    const int b = blockIdx.y, s = blockIdx.z, q0 = blockIdx.x * 64;
    const int skh = SEQK / nsplit;
    const int t = threadIdx.x, wave = t >> 6, lane = t & 63;
    const int lrow = lane & 15, quad = lane >> 4;

    const int valid = valid_lens[b];
    const int vloc  = min(valid - s * skh, skh);

    float* __restrict__ lpart = Lp + (size_t)(s * BATCH + b) * SEQQ + q0;
    float* __restrict__ opart = Op + ((size_t)(s * BATCH + b) * SEQQ + q0) * ODIM;

    if (vloc <= 0) {            // dead split: combine gates O on l>0
        if (t < 64) lpart[t] = 0.f;
        return;
    }

    __shared__ __align__(16) unsigned short Ks[64 * 128];    // 16KB swizzled
    __shared__ __align__(16) unsigned short Vs[128 * 64];    // 16KB swizzled
    __shared__ __align__(16) unsigned short Ps[4][16][72];   // 9.2KB padded

    // Q fragments: rows q0 + wave*16 + lrow
    bf16x8 qf[4];
    {
        const unsigned short* qp =
            Qb + ((size_t)b * SEQQ + q0 + wave * 16 + lrow) * ODIM + quad * 8;
#pragma unroll
        for (int ks = 0; ks < 4; ++ks) qf[ks] = *(const bf16x8*)(qp + ks * 32);
    }

    f32x4 o[8];
#pragma unroll
    for (int nt = 0; nt < 8; ++nt)
#pragma unroll
        for (int i = 0; i < 4; ++i) o[nt][i] = 0.f;
    float lsum[4] = {0.f, 0.f, 0.f, 0.f};

    // staging: K 1024 slots (4/thr): row kr=s>>4, chunk (s&15)^(kr&15)
    //          V 1024 slots (4/thr): row vr=s>>3, chunk (s&7)^(vr&7)
    const unsigned short* kgp[4]; unsigned short* kldst[4];
    const unsigned short* vgp[4]; unsigned short* vldst[4];
    const unsigned short* kbase = Kb + ((size_t)b * SEQK + s * skh) * ODIM;
    const unsigned short* vbase = Vt + (size_t)b * ODIM * SEQK + s * skh;
#pragma unroll
    for (int j = 0; j < 4; ++j) {
        const int sl = j * 256 + t;
        const int kr = sl >> 4, kc = (sl & 15) ^ (kr & 15);
        kgp[j]   = kbase + (size_t)kr * ODIM + kc * 8;
        kldst[j] = &Ks[sl * 8];
        const int vr = sl >> 3, vc = (sl & 7) ^ (vr & 7);
        vgp[j]   = vbase + (size_t)vr * SEQK + vc * 8;
        vldst[j] = &Vs[sl * 8];
    }

    const int x4 = lrow, x3 = lrow & 7;
    const int nch = (vloc + 63) >> 6;

    for (int c = 0; c < nch; ++c) {
        const int k0 = c * 64;
#pragma unroll
        for (int j = 0; j < 4; ++j) {
            gl_lds16(kgp[j] + (size_t)k0 * ODIM, kldst[j]);
            gl_lds16(vgp[j] + k0, vldst[j]);
        }
        __syncthreads();

        // S = Q K^T : rows = Q, key tiles nt
        f32x4 sv[4];
#pragma unroll
        for (int nt = 0; nt < 4; ++nt)
#pragma unroll
            for (int i = 0; i < 4; ++i) sv[nt][i] = 0.f;
#pragma unroll
        for (int ks = 0; ks < 4; ++ks)
#pragma unroll
            for (int nt = 0; nt < 4; ++nt) {
                const int kr = nt * 16 + lrow;
                const int cc = (ks * 4 + quad) ^ x4;
                bf16x8 kf = *(const bf16x8*)&Ks[(kr * 16 + cc) * 8];
                sv[nt] = __builtin_amdgcn_mfma_f32_16x16x32_bf16(qf[ks], kf, sv[nt], 0, 0, 0);
            }

        if (k0 + 64 > vloc) {   // ragged tail
#pragma unroll
            for (int nt = 0; nt < 4; ++nt)
                if (k0 + nt * 16 + lrow >= vloc) {
#pragma unroll
                    for (int i = 0; i < 4; ++i) sv[nt][i] = -1e30f;
                }
        }

        // exp (fp32-safe, scores ~N(0,1)); P -> wave-private LDS
#pragma unroll
        for (int nt = 0; nt < 4; ++nt)
#pragma unroll
            for (int r = 0; r < 4; ++r) {
                float p = __expf(sv[nt][r]);
                lsum[r] += p;
                Ps[wave][quad * 4 + r][nt * 16 + lrow] =
                    (unsigned short)((__float_as_uint(p) + 0x8000u) >> 16);
            }

        bf16x8 pf0 = *(const bf16x8*)&Ps[wave][lrow][quad * 8];
        bf16x8 pf1 = *(const bf16x8*)&Ps[wave][lrow][32 + quad * 8];

        // O += P V : dim tiles nt, 2 k-steps
#pragma unroll
        for (int nt = 0; nt < 8; ++nt) {
            const int vrow = nt * 16 + lrow;
            bf16x8 v0 = *(const bf16x8*)&Vs[(vrow * 8 + (quad ^ x3)) * 8];
            o[nt] = __builtin_amdgcn_mfma_f32_16x16x32_bf16(pf0, v0, o[nt], 0, 0, 0);
        }
#pragma unroll
        for (int nt = 0; nt < 8; ++nt) {
            const int vrow = nt * 16 + lrow;
            bf16x8 v1 = *(const bf16x8*)&Vs[(vrow * 8 + ((4 + quad) ^ x3)) * 8];
            o[nt] = __builtin_amdgcn_mfma_f32_16x16x32_bf16(pf1, v1, o[nt], 0, 0, 0);
        }
        __syncthreads();
    }

    // row sums across the 16 lanes of each quad group
#pragma unroll
    for (int msk = 1; msk < 16; msk <<= 1)
#pragma unroll
        for (int r = 0; r < 4; ++r) lsum[r] += __shfl_xor(lsum[r], msk);
    if (lrow == 0) {
#pragma unroll
        for (int r = 0; r < 4; ++r)
            lpart[wave * 16 + quad * 4 + r] = lsum[r];
    }

#pragma unroll
    for (int nt = 0; nt < 8; ++nt)
#pragma unroll
        for (int r = 0; r < 4; ++r)
            opart[(size_t)(wave * 16 + quad * 4 + r) * ODIM + nt * 16 + lrow]
                = o[nt][r];
}

// ---------------------------------------------------------------------------
// Combine: out = sum_s [l_s>0] O_s / sum_s l_s
// ---------------------------------------------------------------------------
__global__ __launch_bounds__(256)
void combine_kernel(const float* __restrict__ Op, const float* __restrict__ Lp,
                    float* __restrict__ out, int nsplit)
{
    const int idx = blockIdx.x * 256 + threadIdx.x;  // float4 index
    const int row = idx >> 5;
    const size_t SL = (size_t)BATCH * SEQQ;
    float l = 0.f;
    float4 acc = {0.f, 0.f, 0.f, 0.f};
    for (int s = 0; s < nsplit; ++s) {
        float ls = Lp[(size_t)s * SL + row];
        if (ls > 0.f) {
            float4 v = ((const float4*)(Op + (size_t)s * SL * ODIM))[idx];
            acc.x += v.x; acc.y += v.y; acc.z += v.z; acc.w += v.w;
            l += ls;
        }
    }
    const float inv = 1.f / l;
    float4 r;
    r.x = acc.x * inv; r.y = acc.y * inv; r.z = acc.z * inv; r.w = acc.w * inv;
    ((float4*)out)[idx] = r;
}

// ---------------------------------------------------------------------------
extern "C" void kernel_launch(void* const* d_in, const int* in_sizes, int n_in,
                              void* d_out, int out_size, void* d_ws, size_t ws_size,
                              hipStream_t stream)
{
    const float* queries    = (const float*)d_in[0];
    const float* keys       = (const float*)d_in[1];
    const float* values     = (const float*)d_in[2];
    const int*   valid_lens = (const int*)d_in[3];
    const float* w_q        = (const float*)d_in[4];
    const float* b_q        = (const float*)d_in[5];
    const float* w_k        = (const float*)d_in[6];
    const float* b_k        = (const float*)d_in[7];
    const float* w_v        = (const float*)d_in[8];
    const float* b_v        = (const float*)d_in[9];
    float* out = (float*)d_out;

    const size_t nQKV = (size_t)BATCH * SEQQ * ODIM;   // 2,097,152
    unsigned short* Qb = (unsigned short*)d_ws;
    unsigned short* Kb = Qb + nQKV;
    unsigned short* Vt = Kb + nQKV;
    unsigned short* Wt = Vt + nQKV;                    // 3*1024*128 bf16
    const size_t base = 3 * nQKV * sizeof(unsigned short)
                      + (size_t)3 * DMODEL * ODIM * sizeof(unsigned short);

    int KS = 4;
    if (ws_size < base + 4 * (nQKV * 4 + (size_t)BATCH * SEQQ * 4)) KS = 2;

    float* Op = (float*)((char*)d_ws + base);
    float* Lp = Op + (size_t)KS * nQKV;

    wtrans_kernel<<<dim3(DMODEL / 32, ODIM / 32, 3), 256, 0, stream>>>(w_q, w_k, w_v, Wt);

    proj_kernel<<<dim3((BATCH * SEQQ) / 128, 3), 256, 0, stream>>>(
        queries, keys, values, Wt, b_q, b_k, b_v, Qb, Kb, Vt);

    flash_kernel<<<dim3(SEQQ / 64, BATCH, KS), 256, 0, stream>>>(
        Qb, Kb, Vt, valid_lens, Op, Lp, KS);

    combine_kernel<<<(BATCH * SEQQ * ODIM / 4) / 256, 256, 0, stream>>>(Op, Lp, out, KS);
}

// Round 9
// 252.590 us; speedup vs baseline: 1.1869x; 1.1869x over previous
//
#include <hip/hip_runtime.h>
#include <math.h>

// v8: proj = round-2 v3 byte-identical except __launch_bounds__(256,3)->(256,2)
// (E1': lift VGPR cap 85->128, test prefetch-serialization theory).
// flash = 2-phase double-buffered K/V staging (E2, from v7).
// wtrans/combine frozen.

constexpr int BATCH  = 8;
constexpr int SEQQ   = 2048;
constexpr int SEQK   = 2048;
constexpr int DMODEL = 1024;
constexpr int ODIM   = 128;

typedef __attribute__((ext_vector_type(8))) short bf16x8;
typedef __attribute__((ext_vector_type(4))) float f32x4;

__device__ inline unsigned short f2bf(float f) {   // RNE
    union { float f; unsigned int u; } v; v.f = f;
    unsigned int r = v.u + 0x7FFFu + ((v.u >> 16) & 1u);
    return (unsigned short)(r >> 16);
}

// pack two fp32 -> 2 bf16, round-half-up (v_add + v_perm, 3 instr)
__device__ __forceinline__ unsigned int pk2bf(float a, float b) {
    unsigned int ua = __float_as_uint(a) + 0x8000u;
    unsigned int ub = __float_as_uint(b) + 0x8000u;
    return __builtin_amdgcn_perm(ub, ua, 0x07060302u);
}

__device__ __forceinline__ void gl_lds16(const void* g, void* l) {
    __builtin_amdgcn_global_load_lds(
        (const __attribute__((address_space(1))) unsigned int*)g,
        (__attribute__((address_space(3))) unsigned int*)l, 16, 0, 0);
}

// ---------------------------------------------------------------------------
// W[1024][128] fp32  ->  Wt[128][1024] bf16   (x3 via blockIdx.z)
// ---------------------------------------------------------------------------
__global__ __launch_bounds__(256)
void wtrans_kernel(const float* __restrict__ Wq, const float* __restrict__ Wk,
                   const float* __restrict__ Wv, unsigned short* __restrict__ Wt)
{
    const int which = blockIdx.z;
    const float* __restrict__ W = which == 0 ? Wq : (which == 1 ? Wk : Wv);
    unsigned short* __restrict__ dst = Wt + (size_t)which * DMODEL * ODIM;
    const int k0 = blockIdx.x * 32, n0 = blockIdx.y * 32;
    __shared__ unsigned short T[32][36];
    const int t = threadIdx.x;
    const int r = t >> 3, c = (t & 7) * 4;
    float4 w = *(const float4*)(W + (size_t)(k0 + r) * ODIM + n0 + c);
    T[r][c + 0] = f2bf(w.x); T[r][c + 1] = f2bf(w.y);
    T[r][c + 2] = f2bf(w.z); T[r][c + 3] = f2bf(w.w);
    __syncthreads();
    const int n = t >> 3, k4 = (t & 7) * 4;
    ushort4 o;
    o.x = T[k4 + 0][n]; o.y = T[k4 + 1][n];
    o.z = T[k4 + 2][n]; o.w = T[k4 + 3][n];
    *(ushort4*)(dst + (size_t)(n0 + n) * DMODEL + k0 + k4) = o;
}

// ---------------------------------------------------------------------------
// Projection v3 (round-2, measured 80us, passed). ONLY change vs round-2:
// __launch_bounds__(256,3) -> (256,2). VGPR cap 85 -> 128.
// ---------------------------------------------------------------------------
#define PSTEP(T, CUR, REGC, REGN, DO_W, DO_A, DO_WR, WSTR, DO_SYNC)           \
  {                                                                            \
    if (DO_W) {                                                                \
      const int kw = ((T) + 1) * 64;                                           \
      _Pragma("unroll")                                                        \
      for (int j = 0; j < 4; ++j)                                              \
        gl_lds16(wgp[j] + kw, &Ws[(CUR) ^ 1][wloff[j]]);                       \
    }                                                                          \
    if (DO_A) {                                                                \
      const int ka = ((T) + 2) * 64;                                           \
      _Pragma("unroll")                                                        \
      for (int j = 0; j < 4; ++j) REGN[j] = *(const float4*)(agp[j] + ka);     \
    }                                                                          \
    _Pragma("unroll")                                                          \
    for (int ks = 0; ks < 2; ++ks) {                                           \
      const int c = (ks * 4 + quad) ^ x;                                       \
      bf16x8 af0 = *(const bf16x8*)&As[CUR][(wrh + lrow) * 64 + c * 8];        \
      bf16x8 af1 = *(const bf16x8*)&As[CUR][(wrh + 16 + lrow) * 64 + c * 8];   \
      _Pragma("unroll")                                                        \
      for (int nt = 0; nt < 4; ++nt) {                                         \
        const int n = wch + nt * 16 + lrow;                                    \
        bf16x8 wf = *(const bf16x8*)&Ws[CUR][n * 64 + c * 8];                  \
        acc[0][nt] = __builtin_amdgcn_mfma_f32_16x16x32_bf16(af0, wf, acc[0][nt], 0, 0, 0); \
        acc[1][nt] = __builtin_amdgcn_mfma_f32_16x16x32_bf16(af1, wf, acc[1][nt], 0, 0, 0); \
      }                                                                        \
    }                                                                          \
    if (DO_WR) {                                                               \
      _Pragma("unroll")                                                        \
      for (int j = 0; j < 4; ++j) {                                            \
        uint2 p;                                                               \
        p.x = pk2bf(REGC[j].x, REGC[j].y);                                     \
        p.y = pk2bf(REGC[j].z, REGC[j].w);                                     \
        *(uint2*)&As[(CUR) ^ 1][awoff[j]] = p;                                 \
      }                                                                        \
    }                                                                          \
    if (DO_SYNC) {                                                             \
      asm volatile("s_waitcnt " WSTR ::: "memory");                            \
      __builtin_amdgcn_sched_barrier(0);                                       \
      __builtin_amdgcn_s_barrier();                                            \
      __builtin_amdgcn_sched_barrier(0);                                       \
    }                                                                          \
  }

__global__ __launch_bounds__(256, 2)
void proj_kernel(const float* __restrict__ Aq, const float* __restrict__ Ak,
                 const float* __restrict__ Av,
                 const unsigned short* __restrict__ Wt_all,
                 const float* __restrict__ bq, const float* __restrict__ bk,
                 const float* __restrict__ bv,
                 unsigned short* __restrict__ Qb, unsigned short* __restrict__ Kb,
                 unsigned short* __restrict__ Vt)
{
    const int which = blockIdx.y;
    const float* __restrict__ A    = which == 0 ? Aq : (which == 1 ? Ak : Av);
    const float* __restrict__ bias = which == 0 ? bq : (which == 1 ? bk : bv);
    const unsigned short* __restrict__ Wt = Wt_all + (size_t)which * DMODEL * ODIM;

    const int row0 = blockIdx.x * 64;
    const int t = threadIdx.x, wave = t >> 6, lane = t & 63;
    const int lrow = lane & 15, quad = lane >> 4;
    const int wrh = (wave & 1) * 32;    // row-half base
    const int wch = (wave >> 1) * 64;   // col-half base

    __shared__ __align__(16) unsigned short As[2][64 * 64];   // bf16, 8KB/buf
    __shared__ __align__(16) unsigned short Ws[2][128 * 64];  // bf16, 16KB/buf

    f32x4 acc[2][4];
#pragma unroll
    for (int mt = 0; mt < 2; ++mt)
#pragma unroll
        for (int nt = 0; nt < 4; ++nt)
#pragma unroll
            for (int i = 0; i < 4; ++i) acc[mt][nt][i] = 0.f;

    // A: global fp32 -> regs; bf16 swizzled ds_write. 4 float4 / thread.
    const float* agp[4];
    int awoff[4];
#pragma unroll
    for (int j = 0; j < 4; ++j) {
        const int s = j * 256 + t;
        const int ar = s >> 4, ac = s & 15;           // row 0..63, float4-chunk 0..15
        agp[j]   = A + (size_t)(row0 + ar) * DMODEL + ac * 4;
        awoff[j] = ar * 64 + (((ac >> 1) ^ (ar & 7)) * 8) + (ac & 1) * 4;
    }
    // W: gl_lds16, pre-swizzled source, linear dest. 4 / thread.
    const unsigned short* wgp[4];
    int wloff[4];
#pragma unroll
    for (int j = 0; j < 4; ++j) {
        const int s = j * 256 + t;
        const int wr = s >> 3, wcc = (s & 7) ^ (wr & 7);
        wgp[j]   = Wt + (size_t)wr * DMODEL + wcc * 8;
        wloff[j] = s * 8;
    }

    const int x = lrow & 7;
    float4 ra[4], rb[4];

    // ---- prologue: W(0) -> Ws[0]; A(0) -> ra; A(1) -> rb; write A(0) ----
#pragma unroll
    for (int j = 0; j < 4; ++j) gl_lds16(wgp[j], &Ws[0][wloff[j]]);
#pragma unroll
    for (int j = 0; j < 4; ++j) ra[j] = *(const float4*)(agp[j]);
#pragma unroll
    for (int j = 0; j < 4; ++j) rb[j] = *(const float4*)(agp[j] + 64);
#pragma unroll
    for (int j = 0; j < 4; ++j) {
        uint2 p;                                       // auto-waits A(0);
        p.x = pk2bf(ra[j].x, ra[j].y);                 // W(0) older -> done too
        p.y = pk2bf(ra[j].z, ra[j].w);
        *(uint2*)&As[0][awoff[j]] = p;
    }
    asm volatile("s_waitcnt lgkmcnt(0)" ::: "memory");
    __builtin_amdgcn_sched_barrier(0);
    __builtin_amdgcn_s_barrier();
    __builtin_amdgcn_sched_barrier(0);

    // steady state: entering step t, A(t+1) regs in flight; Ws[t&1]/As[t&1] ready
    for (int kt = 0; kt < 14; kt += 2) {
        PSTEP(kt,     0, rb, ra, 1, 1, 1, "vmcnt(4) lgkmcnt(0)", 1);
        PSTEP(kt + 1, 1, ra, rb, 1, 1, 1, "vmcnt(4) lgkmcnt(0)", 1);
    }
    PSTEP(14, 0, rb, ra, 1, 0, 1, "vmcnt(0) lgkmcnt(0)", 1);
    PSTEP(15, 1, ra, rb, 0, 0, 0, "", 0);

    const float sc = (which == 0) ? 0.08838834764831845f : 1.0f;
    float bv_[4];
#pragma unroll
    for (int nt = 0; nt < 4; ++nt) bv_[nt] = bias[wch + nt * 16 + lrow];

    const int b  = row0 >> 11;
    const int mb = row0 & 2047;

    if (which == 2) {
        // V transposed store: Vt[b][n][m]
#pragma unroll
        for (int mt = 0; mt < 2; ++mt)
#pragma unroll
            for (int nt = 0; nt < 4; ++nt) {
                const int n = wch + nt * 16 + lrow;
                ushort4 o;
                o.x = f2bf(acc[mt][nt][0] + bv_[nt]);
                o.y = f2bf(acc[mt][nt][1] + bv_[nt]);
                o.z = f2bf(acc[mt][nt][2] + bv_[nt]);
                o.w = f2bf(acc[mt][nt][3] + bv_[nt]);
                *(ushort4*)(Vt + ((size_t)b * ODIM + n) * SEQK
                            + mb + wrh + mt * 16 + quad * 4) = o;
            }
    } else {
        unsigned short* __restrict__ Ob = (which == 0) ? Qb : Kb;
#pragma unroll
        for (int mt = 0; mt < 2; ++mt)
#pragma unroll
            for (int nt = 0; nt < 4; ++nt)
#pragma unroll
                for (int r = 0; r < 4; ++r) {
                    float val = sc * (acc[mt][nt][r] + bv_[nt]);
                    Ob[(size_t)(row0 + wrh + mt * 16 + quad * 4 + r) * ODIM
                       + wch + nt * 16 + lrow] = f2bf(val);
                }
    }
}

// ---------------------------------------------------------------------------
// Flash attention v2: 2-phase double-buffered K/V staging. Per step:
// issue stage(c+1) FIRST (8 gl_lds16 into buf^1, L2-hot ~300cy), then
// compute step c (32 MFMA + softmax, ~1200cy) from buf, then one
// __syncthreads (implicit vmcnt drain is ~free: loads landed under compute).
// LDS 73.2KB -> 2 blocks/CU. Dead splits exit before any barrier.
// ---------------------------------------------------------------------------
__global__ __launch_bounds__(256, 2)
void flash_kernel(const unsigned short* __restrict__ Qb,
                  const unsigned short* __restrict__ Kb,
                  const unsigned short* __restrict__ Vt,
                  const int* __restrict__ valid_lens,
                  float* __restrict__ Op, float* __restrict__ Lp, int nsplit)
{
    const int b = blockIdx.y, s = blockIdx.z, q0 = blockIdx.x * 64;
    const int skh = SEQK / nsplit;
    const int t = threadIdx.x, wave = t >> 6, lane = t & 63;
    const int lrow = lane & 15, quad = lane >> 4;

    const int valid = valid_lens[b];
    const int vloc  = min(valid - s * skh, skh);

    float* __restrict__ lpart = Lp + (size_t)(s * BATCH + b) * SEQQ + q0;
    float* __restrict__ opart = Op + ((size_t)(s * BATCH + b) * SEQQ + q0) * ODIM;

    if (vloc <= 0) {            // dead split: combine gates O on l>0
        if (t < 64) lpart[t] = 0.f;
        return;
    }

    __shared__ __align__(16) unsigned short Ks[2][64 * 128];  // 2x16KB swizzled
    __shared__ __align__(16) unsigned short Vs[2][128 * 64];  // 2x16KB swizzled
    __shared__ __align__(16) unsigned short Ps[4][16][72];    // 9.2KB padded

    // Q fragments: rows q0 + wave*16 + lrow
    bf16x8 qf[4];
    {
        const unsigned short* qp =
            Qb + ((size_t)b * SEQQ + q0 + wave * 16 + lrow) * ODIM + quad * 8;
#pragma unroll
        for (int ks = 0; ks < 4; ++ks) qf[ks] = *(const bf16x8*)(qp + ks * 32);
    }

    f32x4 o[8];
#pragma unroll
    for (int nt = 0; nt < 8; ++nt)
#pragma unroll
        for (int i = 0; i < 4; ++i) o[nt][i] = 0.f;
    float lsum[4] = {0.f, 0.f, 0.f, 0.f};

    // staging: K 1024 slots (4/thr): row kr=s>>4, chunk (s&15)^(kr&15)
    //          V 1024 slots (4/thr): row vr=s>>3, chunk (s&7)^(vr&7)
    const unsigned short* kgp[4]; int koff[4];
    const unsigned short* vgp[4]; int voff[4];
    const unsigned short* kbase = Kb + ((size_t)b * SEQK + s * skh) * ODIM;
    const unsigned short* vbase = Vt + (size_t)b * ODIM * SEQK + s * skh;
#pragma unroll
    for (int j = 0; j < 4; ++j) {
        const int sl = j * 256 + t;
        const int kr = sl >> 4, kc = (sl & 15) ^ (kr & 15);
        kgp[j]  = kbase + (size_t)kr * ODIM + kc * 8;
        koff[j] = sl * 8;
        const int vr = sl >> 3, vc = (sl & 7) ^ (vr & 7);
        vgp[j]  = vbase + (size_t)vr * SEQK + vc * 8;
        voff[j] = sl * 8;
    }

    const int x4 = lrow, x3 = lrow & 7;
    const int nch = (vloc + 63) >> 6;

    // prologue: stage chunk 0 into buf 0
#pragma unroll
    for (int j = 0; j < 4; ++j) {
        gl_lds16(kgp[j], &Ks[0][koff[j]]);
        gl_lds16(vgp[j], &Vs[0][voff[j]]);
    }
    __syncthreads();

    for (int c = 0; c < nch; ++c) {
        const int cur = c & 1;
        const int k0  = c * 64;

        // issue next chunk's stage FIRST (lands under this step's compute)
        if (c + 1 < nch) {
            const int k1 = (c + 1) * 64;
#pragma unroll
            for (int j = 0; j < 4; ++j) {
                gl_lds16(kgp[j] + (size_t)k1 * ODIM, &Ks[cur ^ 1][koff[j]]);
                gl_lds16(vgp[j] + k1, &Vs[cur ^ 1][voff[j]]);
            }
        }

        // S = Q K^T : rows = Q, key tiles nt
        f32x4 sv[4];
#pragma unroll
        for (int nt = 0; nt < 4; ++nt)
#pragma unroll
            for (int i = 0; i < 4; ++i) sv[nt][i] = 0.f;
#pragma unroll
        for (int ks = 0; ks < 4; ++ks)
#pragma unroll
            for (int nt = 0; nt < 4; ++nt) {
                const int kr = nt * 16 + lrow;
                const int cc = (ks * 4 + quad) ^ x4;
                bf16x8 kf = *(const bf16x8*)&Ks[cur][(kr * 16 + cc) * 8];
                sv[nt] = __builtin_amdgcn_mfma_f32_16x16x32_bf16(qf[ks], kf, sv[nt], 0, 0, 0);
            }

        if (k0 + 64 > vloc) {   // ragged tail
#pragma unroll
            for (int nt = 0; nt < 4; ++nt)
                if (k0 + nt * 16 + lrow >= vloc) {
#pragma unroll
                    for (int i = 0; i < 4; ++i) sv[nt][i] = -1e30f;
                }
        }

        // exp (fp32-safe, scores ~N(0,1)); P -> wave-private LDS
#pragma unroll
        for (int nt = 0; nt < 4; ++nt)
#pragma unroll
            for (int r = 0; r < 4; ++r) {
                float p = __expf(sv[nt][r]);
                lsum[r] += p;
                Ps[wave][quad * 4 + r][nt * 16 + lrow] =
                    (unsigned short)((__float_as_uint(p) + 0x8000u) >> 16);
            }

        bf16x8 pf0 = *(const bf16x8*)&Ps[wave][lrow][quad * 8];
        bf16x8 pf1 = *(const bf16x8*)&Ps[wave][lrow][32 + quad * 8];

        // O += P V : dim tiles nt, 2 k-steps
#pragma unroll
        for (int nt = 0; nt < 8; ++nt) {
            const int vrow = nt * 16 + lrow;
            bf16x8 v0 = *(const bf16x8*)&Vs[cur][(vrow * 8 + (quad ^ x3)) * 8];
            o[nt] = __builtin_amdgcn_mfma_f32_16x16x32_bf16(pf0, v0, o[nt], 0, 0, 0);
        }
#pragma unroll
        for (int nt = 0; nt < 8; ++nt) {
            const int vrow = nt * 16 + lrow;
            bf16x8 v1 = *(const bf16x8*)&Vs[cur][(vrow * 8 + ((4 + quad) ^ x3)) * 8];
            o[nt] = __builtin_amdgcn_mfma_f32_16x16x32_bf16(pf1, v1, o[nt], 0, 0, 0);
        }
        __syncthreads();   // drains next-chunk stage (already landed) + LDS reuse
    }

    // row sums across the 16 lanes of each quad group
#pragma unroll
    for (int msk = 1; msk < 16; msk <<= 1)
#pragma unroll
        for (int r = 0; r < 4; ++r) lsum[r] += __shfl_xor(lsum[r], msk);
    if (lrow == 0) {
#pragma unroll
        for (int r = 0; r < 4; ++r)
            lpart[wave * 16 + quad * 4 + r] = lsum[r];
    }

#pragma unroll
    for (int nt = 0; nt < 8; ++nt)
#pragma unroll
        for (int r = 0; r < 4; ++r)
            opart[(size_t)(wave * 16 + quad * 4 + r) * ODIM + nt * 16 + lrow]
                = o[nt][r];
}

// ---------------------------------------------------------------------------
// Combine: out = sum_s [l_s>0] O_s / sum_s l_s
// ---------------------------------------------------------------------------
__global__ __launch_bounds__(256)
void combine_kernel(const float* __restrict__ Op, const float* __restrict__ Lp,
                    float* __restrict__ out, int nsplit)
{
    const int idx = blockIdx.x * 256 + threadIdx.x;  // float4 index
    const int row = idx >> 5;
    const size_t SL = (size_t)BATCH * SEQQ;
    float l = 0.f;
    float4 acc = {0.f, 0.f, 0.f, 0.f};
    for (int s = 0; s < nsplit; ++s) {
        float ls = Lp[(size_t)s * SL + row];
        if (ls > 0.f) {
            float4 v = ((const float4*)(Op + (size_t)s * SL * ODIM))[idx];
            acc.x += v.x; acc.y += v.y; acc.z += v.z; acc.w += v.w;
            l += ls;
        }
    }
    const float inv = 1.f / l;
    float4 r;
    r.x = acc.x * inv; r.y = acc.y * inv; r.z = acc.z * inv; r.w = acc.w * inv;
    ((float4*)out)[idx] = r;
}

// ---------------------------------------------------------------------------
extern "C" void kernel_launch(void* const* d_in, const int* in_sizes, int n_in,
                              void* d_out, int out_size, void* d_ws, size_t ws_size,
                              hipStream_t stream)
{
    const float* queries    = (const float*)d_in[0];
    const float* keys       = (const float*)d_in[1];
    const float* values     = (const float*)d_in[2];
    const int*   valid_lens = (const int*)d_in[3];
    const float* w_q        = (const float*)d_in[4];
    const float* b_q        = (const float*)d_in[5];
    const float* w_k        = (const float*)d_in[6];
    const float* b_k        = (const float*)d_in[7];
    const float* w_v        = (const float*)d_in[8];
    const float* b_v        = (const float*)d_in[9];
    float* out = (float*)d_out;

    const size_t nQKV = (size_t)BATCH * SEQQ * ODIM;   // 2,097,152
    unsigned short* Qb = (unsigned short*)d_ws;
    unsigned short* Kb = Qb + nQKV;
    unsigned short* Vt = Kb + nQKV;
    unsigned short* Wt = Vt + nQKV;                    // 3*1024*128 bf16
    const size_t base = 3 * nQKV * sizeof(unsigned short)
                      + (size_t)3 * DMODEL * ODIM * sizeof(unsigned short);

    int KS = 4;
    if (ws_size < base + 4 * (nQKV * 4 + (size_t)BATCH * SEQQ * 4)) KS = 2;

    float* Op = (float*)((char*)d_ws + base);
    float* Lp = Op + (size_t)KS * nQKV;

    wtrans_kernel<<<dim3(DMODEL / 32, ODIM / 32, 3), 256, 0, stream>>>(w_q, w_k, w_v, Wt);

    proj_kernel<<<dim3((BATCH * SEQQ) / 64, 3), 256, 0, stream>>>(
        queries, keys, values, Wt, b_q, b_k, b_v, Qb, Kb, Vt);

    flash_kernel<<<dim3(SEQQ / 64, BATCH, KS), 256, 0, stream>>>(
        Qb, Kb, Vt, valid_lens, Op, Lp, KS);

    combine_kernel<<<(BATCH * SEQQ * ODIM / 4) / 256, 256, 0, stream>>>(Op, Lp, out, KS);
}

// Round 10
// 250.028 us; speedup vs baseline: 1.1991x; 1.0102x over previous
//
#include <hip/hip_runtime.h>
#include <math.h>

// v9: proj = round-9 exact (passed, 80us, parked). flash v3 = round-6
// single-buffered flash widened to 8 waves / 512 thr / 128 q-rows per block:
// halves K/V re-staging (134->67 MB), doubles per-barrier work. LDS 50.4KB.
// wtrans/combine frozen.

constexpr int BATCH  = 8;
constexpr int SEQQ   = 2048;
constexpr int SEQK   = 2048;
constexpr int DMODEL = 1024;
constexpr int ODIM   = 128;

typedef __attribute__((ext_vector_type(8))) short bf16x8;
typedef __attribute__((ext_vector_type(4))) float f32x4;

__device__ inline unsigned short f2bf(float f) {   // RNE
    union { float f; unsigned int u; } v; v.f = f;
    unsigned int r = v.u + 0x7FFFu + ((v.u >> 16) & 1u);
    return (unsigned short)(r >> 16);
}

// pack two fp32 -> 2 bf16, round-half-up (v_add + v_perm, 3 instr)
__device__ __forceinline__ unsigned int pk2bf(float a, float b) {
    unsigned int ua = __float_as_uint(a) + 0x8000u;
    unsigned int ub = __float_as_uint(b) + 0x8000u;
    return __builtin_amdgcn_perm(ub, ua, 0x07060302u);
}

__device__ __forceinline__ void gl_lds16(const void* g, void* l) {
    __builtin_amdgcn_global_load_lds(
        (const __attribute__((address_space(1))) unsigned int*)g,
        (__attribute__((address_space(3))) unsigned int*)l, 16, 0, 0);
}

// ---------------------------------------------------------------------------
// W[1024][128] fp32  ->  Wt[128][1024] bf16   (x3 via blockIdx.z)
// ---------------------------------------------------------------------------
__global__ __launch_bounds__(256)
void wtrans_kernel(const float* __restrict__ Wq, const float* __restrict__ Wk,
                   const float* __restrict__ Wv, unsigned short* __restrict__ Wt)
{
    const int which = blockIdx.z;
    const float* __restrict__ W = which == 0 ? Wq : (which == 1 ? Wk : Wv);
    unsigned short* __restrict__ dst = Wt + (size_t)which * DMODEL * ODIM;
    const int k0 = blockIdx.x * 32, n0 = blockIdx.y * 32;
    __shared__ unsigned short T[32][36];
    const int t = threadIdx.x;
    const int r = t >> 3, c = (t & 7) * 4;
    float4 w = *(const float4*)(W + (size_t)(k0 + r) * ODIM + n0 + c);
    T[r][c + 0] = f2bf(w.x); T[r][c + 1] = f2bf(w.y);
    T[r][c + 2] = f2bf(w.z); T[r][c + 3] = f2bf(w.w);
    __syncthreads();
    const int n = t >> 3, k4 = (t & 7) * 4;
    ushort4 o;
    o.x = T[k4 + 0][n]; o.y = T[k4 + 1][n];
    o.z = T[k4 + 2][n]; o.w = T[k4 + 3][n];
    *(ushort4*)(dst + (size_t)(n0 + n) * DMODEL + k0 + k4) = o;
}

// ---------------------------------------------------------------------------
// Projection v3 (round-9 exact: measured 80us, VGPR 68, passed). PARKED.
// ---------------------------------------------------------------------------
#define PSTEP(T, CUR, REGC, REGN, DO_W, DO_A, DO_WR, WSTR, DO_SYNC)           \
  {                                                                            \
    if (DO_W) {                                                                \
      const int kw = ((T) + 1) * 64;                                           \
      _Pragma("unroll")                                                        \
      for (int j = 0; j < 4; ++j)                                              \
        gl_lds16(wgp[j] + kw, &Ws[(CUR) ^ 1][wloff[j]]);                       \
    }                                                                          \
    if (DO_A) {                                                                \
      const int ka = ((T) + 2) * 64;                                           \
      _Pragma("unroll")                                                        \
      for (int j = 0; j < 4; ++j) REGN[j] = *(const float4*)(agp[j] + ka);     \
    }                                                                          \
    _Pragma("unroll")                                                          \
    for (int ks = 0; ks < 2; ++ks) {                                           \
      const int c = (ks * 4 + quad) ^ x;                                       \
      bf16x8 af0 = *(const bf16x8*)&As[CUR][(wrh + lrow) * 64 + c * 8];        \
      bf16x8 af1 = *(const bf16x8*)&As[CUR][(wrh + 16 + lrow) * 64 + c * 8];   \
      _Pragma("unroll")                                                        \
      for (int nt = 0; nt < 4; ++nt) {                                         \
        const int n = wch + nt * 16 + lrow;                                    \
        bf16x8 wf = *(const bf16x8*)&Ws[CUR][n * 64 + c * 8];                  \
        acc[0][nt] = __builtin_amdgcn_mfma_f32_16x16x32_bf16(af0, wf, acc[0][nt], 0, 0, 0); \
        acc[1][nt] = __builtin_amdgcn_mfma_f32_16x16x32_bf16(af1, wf, acc[1][nt], 0, 0, 0); \
      }                                                                        \
    }                                                                          \
    if (DO_WR) {                                                               \
      _Pragma("unroll")                                                        \
      for (int j = 0; j < 4; ++j) {                                            \
        uint2 p;                                                               \
        p.x = pk2bf(REGC[j].x, REGC[j].y);                                     \
        p.y = pk2bf(REGC[j].z, REGC[j].w);                                     \
        *(uint2*)&As[(CUR) ^ 1][awoff[j]] = p;                                 \
      }                                                                        \
    }                                                                          \
    if (DO_SYNC) {                                                             \
      asm volatile("s_waitcnt " WSTR ::: "memory");                            \
      __builtin_amdgcn_sched_barrier(0);                                       \
      __builtin_amdgcn_s_barrier();                                            \
      __builtin_amdgcn_sched_barrier(0);                                       \
    }                                                                          \
  }

__global__ __launch_bounds__(256, 2)
void proj_kernel(const float* __restrict__ Aq, const float* __restrict__ Ak,
                 const float* __restrict__ Av,
                 const unsigned short* __restrict__ Wt_all,
                 const float* __restrict__ bq, const float* __restrict__ bk,
                 const float* __restrict__ bv,
                 unsigned short* __restrict__ Qb, unsigned short* __restrict__ Kb,
                 unsigned short* __restrict__ Vt)
{
    const int which = blockIdx.y;
    const float* __restrict__ A    = which == 0 ? Aq : (which == 1 ? Ak : Av);
    const float* __restrict__ bias = which == 0 ? bq : (which == 1 ? bk : bv);
    const unsigned short* __restrict__ Wt = Wt_all + (size_t)which * DMODEL * ODIM;

    const int row0 = blockIdx.x * 64;
    const int t = threadIdx.x, wave = t >> 6, lane = t & 63;
    const int lrow = lane & 15, quad = lane >> 4;
    const int wrh = (wave & 1) * 32;    // row-half base
    const int wch = (wave >> 1) * 64;   // col-half base

    __shared__ __align__(16) unsigned short As[2][64 * 64];   // bf16, 8KB/buf
    __shared__ __align__(16) unsigned short Ws[2][128 * 64];  // bf16, 16KB/buf

    f32x4 acc[2][4];
#pragma unroll
    for (int mt = 0; mt < 2; ++mt)
#pragma unroll
        for (int nt = 0; nt < 4; ++nt)
#pragma unroll
            for (int i = 0; i < 4; ++i) acc[mt][nt][i] = 0.f;

    // A: global fp32 -> regs; bf16 swizzled ds_write. 4 float4 / thread.
    const float* agp[4];
    int awoff[4];
#pragma unroll
    for (int j = 0; j < 4; ++j) {
        const int s = j * 256 + t;
        const int ar = s >> 4, ac = s & 15;           // row 0..63, float4-chunk 0..15
        agp[j]   = A + (size_t)(row0 + ar) * DMODEL + ac * 4;
        awoff[j] = ar * 64 + (((ac >> 1) ^ (ar & 7)) * 8) + (ac & 1) * 4;
    }
    // W: gl_lds16, pre-swizzled source, linear dest. 4 / thread.
    const unsigned short* wgp[4];
    int wloff[4];
#pragma unroll
    for (int j = 0; j < 4; ++j) {
        const int s = j * 256 + t;
        const int wr = s >> 3, wcc = (s & 7) ^ (wr & 7);
        wgp[j]   = Wt + (size_t)wr * DMODEL + wcc * 8;
        wloff[j] = s * 8;
    }

    const int x = lrow & 7;
    float4 ra[4], rb[4];

    // ---- prologue: W(0) -> Ws[0]; A(0) -> ra; A(1) -> rb; write A(0) ----
#pragma unroll
    for (int j = 0; j < 4; ++j) gl_lds16(wgp[j], &Ws[0][wloff[j]]);
#pragma unroll
    for (int j = 0; j < 4; ++j) ra[j] = *(const float4*)(agp[j]);
#pragma unroll
    for (int j = 0; j < 4; ++j) rb[j] = *(const float4*)(agp[j] + 64);
#pragma unroll
    for (int j = 0; j < 4; ++j) {
        uint2 p;                                       // auto-waits A(0);
        p.x = pk2bf(ra[j].x, ra[j].y);                 // W(0) older -> done too
        p.y = pk2bf(ra[j].z, ra[j].w);
        *(uint2*)&As[0][awoff[j]] = p;
    }
    asm volatile("s_waitcnt lgkmcnt(0)" ::: "memory");
    __builtin_amdgcn_sched_barrier(0);
    __builtin_amdgcn_s_barrier();
    __builtin_amdgcn_sched_barrier(0);

    // steady state: entering step t, A(t+1) regs in flight; Ws[t&1]/As[t&1] ready
    for (int kt = 0; kt < 14; kt += 2) {
        PSTEP(kt,     0, rb, ra, 1, 1, 1, "vmcnt(4) lgkmcnt(0)", 1);
        PSTEP(kt + 1, 1, ra, rb, 1, 1, 1, "vmcnt(4) lgkmcnt(0)", 1);
    }
    PSTEP(14, 0, rb, ra, 1, 0, 1, "vmcnt(0) lgkmcnt(0)", 1);
    PSTEP(15, 1, ra, rb, 0, 0, 0, "", 0);

    const float sc = (which == 0) ? 0.08838834764831845f : 1.0f;
    float bv_[4];
#pragma unroll
    for (int nt = 0; nt < 4; ++nt) bv_[nt] = bias[wch + nt * 16 + lrow];

    const int b  = row0 >> 11;
    const int mb = row0 & 2047;

    if (which == 2) {
        // V transposed store: Vt[b][n][m]
#pragma unroll
        for (int mt = 0; mt < 2; ++mt)
#pragma unroll
            for (int nt = 0; nt < 4; ++nt) {
                const int n = wch + nt * 16 + lrow;
                ushort4 o;
                o.x = f2bf(acc[mt][nt][0] + bv_[nt]);
                o.y = f2bf(acc[mt][nt][1] + bv_[nt]);
                o.z = f2bf(acc[mt][nt][2] + bv_[nt]);
                o.w = f2bf(acc[mt][nt][3] + bv_[nt]);
                *(ushort4*)(Vt + ((size_t)b * ODIM + n) * SEQK
                            + mb + wrh + mt * 16 + quad * 4) = o;
            }
    } else {
        unsigned short* __restrict__ Ob = (which == 0) ? Qb : Kb;
#pragma unroll
        for (int mt = 0; mt < 2; ++mt)
#pragma unroll
            for (int nt = 0; nt < 4; ++nt)
#pragma unroll
                for (int r = 0; r < 4; ++r) {
                    float val = sc * (acc[mt][nt][r] + bv_[nt]);
                    Ob[(size_t)(row0 + wrh + mt * 16 + quad * 4 + r) * ODIM
                       + wch + nt * 16 + lrow] = f2bf(val);
                }
    }
}

// ---------------------------------------------------------------------------
// Flash attention v3: 8 waves x 512 thr, 128 q-rows / block. Single-buffered
// K/V staging (round-6 code per-wave-identical; wave = 0..7 -> rows 0..127,
// staging 2 slots/thread). Halves K/V re-staging vs 64-row blocks.
// LDS 50.4KB (Ks 16K + Vs 16K + Ps[8] 18.4K). Grid (16, 8, KS).
// ---------------------------------------------------------------------------
__global__ __launch_bounds__(512)
void flash_kernel(const unsigned short* __restrict__ Qb,
                  const unsigned short* __restrict__ Kb,
                  const unsigned short* __restrict__ Vt,
                  const int* __restrict__ valid_lens,
                  float* __restrict__ Op, float* __restrict__ Lp, int nsplit)
{
    const int b = blockIdx.y, s = blockIdx.z, q0 = blockIdx.x * 128;
    const int skh = SEQK / nsplit;
    const int t = threadIdx.x, wave = t >> 6, lane = t & 63;
    const int lrow = lane & 15, quad = lane >> 4;

    const int valid = valid_lens[b];
    const int vloc  = min(valid - s * skh, skh);

    float* __restrict__ lpart = Lp + (size_t)(s * BATCH + b) * SEQQ + q0;
    float* __restrict__ opart = Op + ((size_t)(s * BATCH + b) * SEQQ + q0) * ODIM;

    if (vloc <= 0) {            // dead split: combine gates O on l>0
        if (t < 128) lpart[t] = 0.f;
        return;
    }

    __shared__ __align__(16) unsigned short Ks[64 * 128];    // 16KB swizzled
    __shared__ __align__(16) unsigned short Vs[128 * 64];    // 16KB swizzled
    __shared__ __align__(16) unsigned short Ps[8][16][72];   // 18.4KB padded

    // Q fragments: rows q0 + wave*16 + lrow  (wave 0..7 -> 128 rows)
    bf16x8 qf[4];
    {
        const unsigned short* qp =
            Qb + ((size_t)b * SEQQ + q0 + wave * 16 + lrow) * ODIM + quad * 8;
#pragma unroll
        for (int ks = 0; ks < 4; ++ks) qf[ks] = *(const bf16x8*)(qp + ks * 32);
    }

    f32x4 o[8];
#pragma unroll
    for (int nt = 0; nt < 8; ++nt)
#pragma unroll
        for (int i = 0; i < 4; ++i) o[nt][i] = 0.f;
    float lsum[4] = {0.f, 0.f, 0.f, 0.f};

    // staging: K 1024 slots (2/thr): row kr=sl>>4, chunk (sl&15)^(kr&15)
    //          V 1024 slots (2/thr): row vr=sl>>3, chunk (sl&7)^(vr&7)
    const unsigned short* kgp[2]; unsigned short* kldst[2];
    const unsigned short* vgp[2]; unsigned short* vldst[2];
    const unsigned short* kbase = Kb + ((size_t)b * SEQK + s * skh) * ODIM;
    const unsigned short* vbase = Vt + (size_t)b * ODIM * SEQK + s * skh;
#pragma unroll
    for (int j = 0; j < 2; ++j) {
        const int sl = j * 512 + t;
        const int kr = sl >> 4, kc = (sl & 15) ^ (kr & 15);
        kgp[j]   = kbase + (size_t)kr * ODIM + kc * 8;
        kldst[j] = &Ks[sl * 8];
        const int vr = sl >> 3, vc = (sl & 7) ^ (vr & 7);
        vgp[j]   = vbase + (size_t)vr * SEQK + vc * 8;
        vldst[j] = &Vs[sl * 8];
    }

    const int x4 = lrow, x3 = lrow & 7;
    const int nch = (vloc + 63) >> 6;

    for (int c = 0; c < nch; ++c) {
        const int k0 = c * 64;
#pragma unroll
        for (int j = 0; j < 2; ++j) {
            gl_lds16(kgp[j] + (size_t)k0 * ODIM, kldst[j]);
            gl_lds16(vgp[j] + k0, vldst[j]);
        }
        __syncthreads();

        // S = Q K^T : rows = Q, key tiles nt
        f32x4 sv[4];
#pragma unroll
        for (int nt = 0; nt < 4; ++nt)
#pragma unroll
            for (int i = 0; i < 4; ++i) sv[nt][i] = 0.f;
#pragma unroll
        for (int ks = 0; ks < 4; ++ks)
#pragma unroll
            for (int nt = 0; nt < 4; ++nt) {
                const int kr = nt * 16 + lrow;
                const int cc = (ks * 4 + quad) ^ x4;
                bf16x8 kf = *(const bf16x8*)&Ks[(kr * 16 + cc) * 8];
                sv[nt] = __builtin_amdgcn_mfma_f32_16x16x32_bf16(qf[ks], kf, sv[nt], 0, 0, 0);
            }

        if (k0 + 64 > vloc) {   // ragged tail
#pragma unroll
            for (int nt = 0; nt < 4; ++nt)
                if (k0 + nt * 16 + lrow >= vloc) {
#pragma unroll
                    for (int i = 0; i < 4; ++i) sv[nt][i] = -1e30f;
                }
        }

        // exp (fp32-safe, scores ~N(0,1)); P -> wave-private LDS
#pragma unroll
        for (int nt = 0; nt < 4; ++nt)
#pragma unroll
            for (int r = 0; r < 4; ++r) {
                float p = __expf(sv[nt][r]);
                lsum[r] += p;
                Ps[wave][quad * 4 + r][nt * 16 + lrow] =
                    (unsigned short)((__float_as_uint(p) + 0x8000u) >> 16);
            }

        bf16x8 pf0 = *(const bf16x8*)&Ps[wave][lrow][quad * 8];
        bf16x8 pf1 = *(const bf16x8*)&Ps[wave][lrow][32 + quad * 8];

        // O += P V : dim tiles nt, 2 k-steps
#pragma unroll
        for (int nt = 0; nt < 8; ++nt) {
            const int vrow = nt * 16 + lrow;
            bf16x8 v0 = *(const bf16x8*)&Vs[(vrow * 8 + (quad ^ x3)) * 8];
            o[nt] = __builtin_amdgcn_mfma_f32_16x16x32_bf16(pf0, v0, o[nt], 0, 0, 0);
        }
#pragma unroll
        for (int nt = 0; nt < 8; ++nt) {
            const int vrow = nt * 16 + lrow;
            bf16x8 v1 = *(const bf16x8*)&Vs[(vrow * 8 + ((4 + quad) ^ x3)) * 8];
            o[nt] = __builtin_amdgcn_mfma_f32_16x16x32_bf16(pf1, v1, o[nt], 0, 0, 0);
        }
        __syncthreads();
    }

    // row sums across the 16 lanes of each quad group
#pragma unroll
    for (int msk = 1; msk < 16; msk <<= 1)
#pragma unroll
        for (int r = 0; r < 4; ++r) lsum[r] += __shfl_xor(lsum[r], msk);
    if (lrow == 0) {
#pragma unroll
        for (int r = 0; r < 4; ++r)
            lpart[wave * 16 + quad * 4 + r] = lsum[r];
    }

#pragma unroll
    for (int nt = 0; nt < 8; ++nt)
#pragma unroll
        for (int r = 0; r < 4; ++r)
            opart[(size_t)(wave * 16 + quad * 4 + r) * ODIM + nt * 16 + lrow]
                = o[nt][r];
}

// ---------------------------------------------------------------------------
// Combine: out = sum_s [l_s>0] O_s / sum_s l_s
// ---------------------------------------------------------------------------
__global__ __launch_bounds__(256)
void combine_kernel(const float* __restrict__ Op, const float* __restrict__ Lp,
                    float* __restrict__ out, int nsplit)
{
    const int idx = blockIdx.x * 256 + threadIdx.x;  // float4 index
    const int row = idx >> 5;
    const size_t SL = (size_t)BATCH * SEQQ;
    float l = 0.f;
    float4 acc = {0.f, 0.f, 0.f, 0.f};
    for (int s = 0; s < nsplit; ++s) {
        float ls = Lp[(size_t)s * SL + row];
        if (ls > 0.f) {
            float4 v = ((const float4*)(Op + (size_t)s * SL * ODIM))[idx];
            acc.x += v.x; acc.y += v.y; acc.z += v.z; acc.w += v.w;
            l += ls;
        }
    }
    const float inv = 1.f / l;
    float4 r;
    r.x = acc.x * inv; r.y = acc.y * inv; r.z = acc.z * inv; r.w = acc.w * inv;
    ((float4*)out)[idx] = r;
}

// ---------------------------------------------------------------------------
extern "C" void kernel_launch(void* const* d_in, const int* in_sizes, int n_in,
                              void* d_out, int out_size, void* d_ws, size_t ws_size,
                              hipStream_t stream)
{
    const float* queries    = (const float*)d_in[0];
    const float* keys       = (const float*)d_in[1];
    const float* values     = (const float*)d_in[2];
    const int*   valid_lens = (const int*)d_in[3];
    const float* w_q        = (const float*)d_in[4];
    const float* b_q        = (const float*)d_in[5];
    const float* w_k        = (const float*)d_in[6];
    const float* b_k        = (const float*)d_in[7];
    const float* w_v        = (const float*)d_in[8];
    const float* b_v        = (const float*)d_in[9];
    float* out = (float*)d_out;

    const size_t nQKV = (size_t)BATCH * SEQQ * ODIM;   // 2,097,152
    unsigned short* Qb = (unsigned short*)d_ws;
    unsigned short* Kb = Qb + nQKV;
    unsigned short* Vt = Kb + nQKV;
    unsigned short* Wt = Vt + nQKV;                    // 3*1024*128 bf16
    const size_t base = 3 * nQKV * sizeof(unsigned short)
                      + (size_t)3 * DMODEL * ODIM * sizeof(unsigned short);

    int KS = 4;
    if (ws_size < base + 4 * (nQKV * 4 + (size_t)BATCH * SEQQ * 4)) KS = 2;

    float* Op = (float*)((char*)d_ws + base);
    float* Lp = Op + (size_t)KS * nQKV;

    wtrans_kernel<<<dim3(DMODEL / 32, ODIM / 32, 3), 256, 0, stream>>>(w_q, w_k, w_v, Wt);

    proj_kernel<<<dim3((BATCH * SEQQ) / 64, 3), 256, 0, stream>>>(
        queries, keys, values, Wt, b_q, b_k, b_v, Qb, Kb, Vt);

    flash_kernel<<<dim3(SEQQ / 128, BATCH, KS), 512, 0, stream>>>(
        Qb, Kb, Vt, valid_lens, Op, Lp, KS);

    combine_kernel<<<(BATCH * SEQQ * ODIM / 4) / 256, 256, 0, stream>>>(Op, Lp, out, KS);
}